// Round 1
// baseline (896.889 us; speedup 1.0000x reference)
//
#include <hip/hip_runtime.h>
#include <cstdio>
#include <cstdint>

// ---------------------------------------------------------------------------
// MultiHeadSelfAttention (B=2, L=2048, D=512, H=8), per-head full-DxD projs.
// All GEMMs: NT (A[m,k], B[n,k] both k-contiguous), 128x128 tile, BK=32,
// 4 waves (2x2), each wave 64x64 via 4x4 grid of v_mfma_f32_16x16x32_bf16.
// fp32 accumulate everywhere; softmax in fp32.
// ---------------------------------------------------------------------------

#define AS1 __attribute__((address_space(1)))
#define AS3 __attribute__((address_space(3)))

typedef __attribute__((ext_vector_type(8))) short bf16x8;   // 8 bf16 = 4 VGPRs
typedef __attribute__((ext_vector_type(4))) short short4v;  // 4 bf16 = 8 B
typedef __attribute__((ext_vector_type(4))) float f32x4;    // MFMA acc

constexpr int cB = 2, cH = 8, cL = 2048, cD = 512;
constexpr float SCORE_SCALE = 0.044194173824159216f; // 1/sqrt(512)

__device__ __forceinline__ short f2bf(float f) {
  return __builtin_bit_cast(short, static_cast<__bf16>(f)); // RNE convert
}

__device__ __forceinline__ void gload16(const void* g, void* l) {
  // async global->LDS, 16B per lane; LDS dest is wave-uniform base + lane*16
  __builtin_amdgcn_global_load_lds((AS1 const void*)g, (AS3 void*)l, 16, 0, 0);
}

// --------------------------- fp32 -> bf16 convert ---------------------------
__global__ __launch_bounds__(256) void cvt_bf16(const float4* __restrict__ src,
                                                short4v* __restrict__ dst) {
  const int i = blockIdx.x * 256 + threadIdx.x;
  const float4 v = src[i];
  short4v o = { f2bf(v.x), f2bf(v.y), f2bf(v.z), f2bf(v.w) };
  dst[i] = o;
}

// ------------------------------- GEMM modes ---------------------------------
enum { M_PROJ = 0, M_PROJV = 1, M_SCORES = 2, M_CTX = 3, M_OUT = 4 };

template <int MODE>
__global__ __launch_bounds__(256) void gemm_nt(const void* __restrict__ Ap,
                                               const short* __restrict__ Bp,
                                               void* __restrict__ Cp) {
  constexpr int K = (MODE == M_CTX) ? 2048 : (MODE == M_OUT) ? 4096 : 512;

  __shared__ short As[128 * 32];  // 8 KB
  __shared__ short Bs[128 * 32];  // 8 KB

  const int t = threadIdx.x;
  const int lane = t & 63;
  const int wv = t >> 6;          // wave 0..3
  const int wm = wv >> 1, wn = wv & 1;
  const int z = blockIdx.z;

  size_t Aoff, Boff;
  if constexpr (MODE == M_PROJ || MODE == M_PROJV) {
    Aoff = (size_t)(z >> 3) * ((size_t)cL * cD);   // per-b input
    Boff = (size_t)(z & 7) * ((size_t)cD * cD);    // per-h weight
  } else if constexpr (MODE == M_SCORES) {
    Aoff = (size_t)z * ((size_t)cL * cD);          // qh[b,h]
    Boff = (size_t)z * ((size_t)cL * cD);          // kh[b,h]
  } else if constexpr (MODE == M_CTX) {
    Aoff = (size_t)z * ((size_t)cL * cL);          // attn[b,h] (fp32)
    Boff = (size_t)z * ((size_t)cD * cL);          // vhT[b,h]
  } else {                                         // M_OUT
    Aoff = (size_t)z * ((size_t)cL * (cH * cD));   // comb[b]
    Boff = 0;                                      // Wo
  }

  const short* Bg = Bp + Boff + (size_t)(blockIdx.x * 128) * K;

  f32x4 acc[4][4];
#pragma unroll
  for (int i = 0; i < 4; ++i)
#pragma unroll
    for (int j = 0; j < 4; ++j) acc[i][j] = (f32x4){0.f, 0.f, 0.f, 0.f};

  for (int kt = 0; kt < K; kt += 32) {
    __syncthreads();  // LDS safe to overwrite
    // ---- stage A tile (128 rows x 32 k) ----
    if constexpr (MODE == M_CTX) {
      // fp32 source (attn), convert to bf16 while staging
      const float* Ag = (const float*)Ap + Aoff + (size_t)(blockIdx.y * 128) * K + kt;
#pragma unroll
      for (int r = 0; r < 4; ++r) {
        const int c = r * 256 + t;              // 0..1023 float4 chunks
        const int row = c >> 3, col = (c & 7) * 4;
        const float4 vv = *(const float4*)(Ag + (size_t)row * K + col);
        short4v o = { f2bf(vv.x), f2bf(vv.y), f2bf(vv.z), f2bf(vv.w) };
        *(short4v*)&As[row * 32 + col] = o;
      }
    } else {
      const short* Ag = (const short*)Ap + Aoff + (size_t)(blockIdx.y * 128) * K + kt;
#pragma unroll
      for (int r = 0; r < 2; ++r) {
        const int cbase = r * 256 + wv * 64;    // wave-uniform chunk base
        const int c = cbase + lane;             // 0..511 16B chunks
        const int row = c >> 2, col = (c & 3) * 8;
        gload16(Ag + (size_t)row * K + col, &As[cbase * 8]);
      }
    }
    // ---- stage B tile (always bf16) ----
    {
      const short* Bgk = Bg + kt;
#pragma unroll
      for (int r = 0; r < 2; ++r) {
        const int cbase = r * 256 + wv * 64;
        const int c = cbase + lane;
        const int row = c >> 2, col = (c & 3) * 8;
        gload16(Bgk + (size_t)row * K + col, &Bs[cbase * 8]);
      }
    }
    __syncthreads();  // staging complete (compiler drains vmcnt/lgkmcnt)

    // ---- compute: 4x4 MFMA tiles per wave ----
    const int koff = (lane >> 4) * 8;           // A/B frag: k = quad*8 + j
    const int ar = wm * 64 + (lane & 15);
    const int br = wn * 64 + (lane & 15);
    bf16x8 af[4], bfv[4];
#pragma unroll
    for (int i = 0; i < 4; ++i) af[i] = *(const bf16x8*)&As[(ar + i * 16) * 32 + koff];
#pragma unroll
    for (int j = 0; j < 4; ++j) bfv[j] = *(const bf16x8*)&Bs[(br + j * 16) * 32 + koff];
#pragma unroll
    for (int i = 0; i < 4; ++i)
#pragma unroll
      for (int j = 0; j < 4; ++j)
        acc[i][j] = __builtin_amdgcn_mfma_f32_16x16x32_bf16(af[i], bfv[j], acc[i][j], 0, 0, 0);
  }

  // ---- epilogue: C/D layout col=lane&15, row=(lane>>4)*4+reg ----
  const int r0 = (lane >> 4) * 4;
  const int cc = lane & 15;
  const int rowbase = blockIdx.y * 128 + wm * 64 + r0;
  const int colbase = blockIdx.x * 128 + wn * 64 + cc;

  if constexpr (MODE == M_PROJ) {
    short* C = (short*)Cp + (size_t)z * ((size_t)cL * cD);
#pragma unroll
    for (int i = 0; i < 4; ++i)
#pragma unroll
      for (int j = 0; j < 4; ++j)
#pragma unroll
        for (int r = 0; r < 4; ++r)
          C[(size_t)(rowbase + i * 16 + r) * cD + (colbase + j * 16)] = f2bf(acc[i][j][r]);
  } else if constexpr (MODE == M_PROJV) {
    // store transposed: vhT[e][l]; regs r are consecutive l -> pack 4 bf16
    short* C = (short*)Cp + (size_t)z * ((size_t)cD * cL);
#pragma unroll
    for (int i = 0; i < 4; ++i)
#pragma unroll
      for (int j = 0; j < 4; ++j) {
        short4v o = { f2bf(acc[i][j][0]), f2bf(acc[i][j][1]),
                      f2bf(acc[i][j][2]), f2bf(acc[i][j][3]) };
        *(short4v*)&C[(size_t)(colbase + j * 16) * cL + (rowbase + i * 16)] = o;
      }
  } else if constexpr (MODE == M_SCORES) {
    float* C = (float*)Cp + (size_t)z * ((size_t)cL * cL);
#pragma unroll
    for (int i = 0; i < 4; ++i)
#pragma unroll
      for (int j = 0; j < 4; ++j)
#pragma unroll
        for (int r = 0; r < 4; ++r)
          C[(size_t)(rowbase + i * 16 + r) * cL + (colbase + j * 16)] =
              acc[i][j][r] * SCORE_SCALE;
  } else if constexpr (MODE == M_CTX) {
    // write into comb layout: j = (e>>6)*512 + h*64 + (e&63)
    short* C = (short*)Cp + (size_t)(z >> 3) * ((size_t)cL * (cH * cD));
    const int h = z & 7;
#pragma unroll
    for (int i = 0; i < 4; ++i)
#pragma unroll
      for (int j = 0; j < 4; ++j) {
        const int e = colbase + j * 16;
        const int jc = ((e >> 6) << 9) + (h << 6) + (e & 63);
#pragma unroll
        for (int r = 0; r < 4; ++r)
          C[(size_t)(rowbase + i * 16 + r) * (cH * cD) + jc] = f2bf(acc[i][j][r]);
      }
  } else {  // M_OUT: fp32 into d_out
    float* C = (float*)Cp + (size_t)z * ((size_t)cL * cD);
#pragma unroll
    for (int i = 0; i < 4; ++i)
#pragma unroll
      for (int j = 0; j < 4; ++j)
#pragma unroll
        for (int r = 0; r < 4; ++r)
          C[(size_t)(rowbase + i * 16 + r) * cD + (colbase + j * 16)] = acc[i][j][r];
  }
}

// ----------------------- row softmax, fp32, in place ------------------------
__global__ __launch_bounds__(256) void softmax_rows(float* __restrict__ attn) {
  float* p = attn + (size_t)blockIdx.x * cL;
  const int t = threadIdx.x;
  float4 v0 = ((float4*)p)[t];
  float4 v1 = ((float4*)p)[t + 256];

  float m = fmaxf(fmaxf(fmaxf(v0.x, v0.y), fmaxf(v0.z, v0.w)),
                  fmaxf(fmaxf(v1.x, v1.y), fmaxf(v1.z, v1.w)));
#pragma unroll
  for (int off = 32; off; off >>= 1) m = fmaxf(m, __shfl_xor(m, off, 64));
  __shared__ float redm[4];
  __shared__ float reds[4];
  if ((t & 63) == 0) redm[t >> 6] = m;
  __syncthreads();
  m = fmaxf(fmaxf(redm[0], redm[1]), fmaxf(redm[2], redm[3]));

  v0.x = __expf(v0.x - m); v0.y = __expf(v0.y - m);
  v0.z = __expf(v0.z - m); v0.w = __expf(v0.w - m);
  v1.x = __expf(v1.x - m); v1.y = __expf(v1.y - m);
  v1.z = __expf(v1.z - m); v1.w = __expf(v1.w - m);
  float s = v0.x + v0.y + v0.z + v0.w + v1.x + v1.y + v1.z + v1.w;
#pragma unroll
  for (int off = 32; off; off >>= 1) s += __shfl_xor(s, off, 64);
  if ((t & 63) == 0) reds[t >> 6] = s;
  __syncthreads();
  s = reds[0] + reds[1] + reds[2] + reds[3];

  const float inv = 1.0f / s;
  v0.x *= inv; v0.y *= inv; v0.z *= inv; v0.w *= inv;
  v1.x *= inv; v1.y *= inv; v1.z *= inv; v1.w *= inv;
  ((float4*)p)[t] = v0;
  ((float4*)p)[t + 256] = v1;
}

// --------------------------------- launch -----------------------------------
extern "C" void kernel_launch(void* const* d_in, const int* in_sizes, int n_in,
                              void* d_out, int out_size, void* d_ws, size_t ws_size,
                              hipStream_t stream) {
  (void)in_sizes; (void)n_in; (void)out_size;

  const float* q  = (const float*)d_in[0];
  const float* k  = (const float*)d_in[1];
  const float* v  = (const float*)d_in[2];
  const float* Wq = (const float*)d_in[3];
  const float* Wk = (const float*)d_in[4];
  const float* Wv = (const float*)d_in[5];
  const float* Wo = (const float*)d_in[6];

  float* out  = (float*)d_out;
  float* attn = out + (size_t)cB * cL * cD;  // 2,097,152 floats in

  constexpr size_t Mi = 1ull << 20;
  char* ws = (char*)d_ws;
  // every tensor below is exactly 2,097,152 elements (4 MiB bf16) except the
  // 32 MiB activations
  short* qbf = (short*)(ws + 0 * Mi);
  short* kbf = (short*)(ws + 4 * Mi);
  short* vbf = (short*)(ws + 8 * Mi);
  short* wqb = (short*)(ws + 12 * Mi);
  short* wkb = (short*)(ws + 16 * Mi);
  short* wvb = (short*)(ws + 20 * Mi);
  short* wob = (short*)(ws + 24 * Mi);
  short* qh  = (short*)(ws + 28 * Mi);  // 32 MiB; dead after scores
  short* kh  = (short*)(ws + 60 * Mi);  // 32 MiB
  short* vhT = (short*)(ws + 92 * Mi);  // 32 MiB
  short* comb = qh;                     // alias: comb written after qh is dead

  if (ws_size < 124 * Mi) {
    fprintf(stderr, "kernel_launch: ws too small (%zu < %zu)\n", ws_size, 124 * Mi);
    return;
  }

  // 1) convert inputs/weights to bf16 (each tensor = 524288 float4s)
  cvt_bf16<<<2048, 256, 0, stream>>>((const float4*)q,  (short4v*)qbf);
  cvt_bf16<<<2048, 256, 0, stream>>>((const float4*)k,  (short4v*)kbf);
  cvt_bf16<<<2048, 256, 0, stream>>>((const float4*)v,  (short4v*)vbf);
  cvt_bf16<<<2048, 256, 0, stream>>>((const float4*)Wq, (short4v*)wqb);
  cvt_bf16<<<2048, 256, 0, stream>>>((const float4*)Wk, (short4v*)wkb);
  cvt_bf16<<<2048, 256, 0, stream>>>((const float4*)Wv, (short4v*)wvb);
  cvt_bf16<<<2048, 256, 0, stream>>>((const float4*)Wo, (short4v*)wob);

  // 2) per-head projections (z = b*8+h), M=2048 N=512 K=512
  gemm_nt<M_PROJ ><<<dim3(4, 16, 16), 256, 0, stream>>>(qbf, wqb, qh);
  gemm_nt<M_PROJ ><<<dim3(4, 16, 16), 256, 0, stream>>>(kbf, wkb, kh);
  gemm_nt<M_PROJV><<<dim3(4, 16, 16), 256, 0, stream>>>(vbf, wvb, vhT);

  // 3) scores -> d_out attn region (fp32, scaled), M=N=2048 K=512
  gemm_nt<M_SCORES><<<dim3(16, 16, 16), 256, 0, stream>>>(qh, kh, attn);

  // 4) softmax rows in place (32768 rows)
  softmax_rows<<<cB * cH * cL, 256, 0, stream>>>(attn);

  // 5) ctx = attn @ vh, written in comb-permuted layout; M=2048 N=512 K=2048
  gemm_nt<M_CTX><<<dim3(4, 16, 16), 256, 0, stream>>>(attn, vhT, comb);

  // 6) out = comb @ Wo^T; M=2048 N=512 K=4096, z=b
  gemm_nt<M_OUT><<<dim3(4, 16, 2), 256, 0, stream>>>(comb, wob, out);
}

// Round 3
// 822.669 us; speedup vs baseline: 1.0902x; 1.0902x over previous
//
#include <hip/hip_runtime.h>
#include <cstdio>
#include <cstdint>

// ---------------------------------------------------------------------------
// MultiHeadSelfAttention (B=2, L=2048, D=512, H=8), per-head full-DxD projs.
// R3 = R2 with the add_halves pointer-cast compile fix.
// R2: fused normalize+ctx (in-place attn, x=1 grid), row_stats kernel,
//     merged cvt, split-K out-GEMM, XOR bank-swizzle in fused kernel.
// ---------------------------------------------------------------------------

#define AS1 __attribute__((address_space(1)))
#define AS3 __attribute__((address_space(3)))

typedef __attribute__((ext_vector_type(8))) short bf16x8;   // 8 bf16 = 4 VGPRs
typedef __attribute__((ext_vector_type(4))) short short4v;  // 4 bf16 = 8 B
typedef __attribute__((ext_vector_type(4))) float f32x4;    // MFMA acc

constexpr int cB = 2, cH = 8, cL = 2048, cD = 512;
constexpr float SCORE_SCALE = 0.044194173824159216f; // 1/sqrt(512)

__device__ __forceinline__ short f2bf(float f) {
  return __builtin_bit_cast(short, static_cast<__bf16>(f)); // RNE convert
}

__device__ __forceinline__ void gload16(const void* g, void* l) {
  // async global->LDS, 16B per lane; LDS dest is wave-uniform base + lane*16
  __builtin_amdgcn_global_load_lds((AS1 const void*)g, (AS3 void*)l, 16, 0, 0);
}

// --------------------------- fp32 -> bf16 convert (merged) ------------------
struct CvtArgs { const float4* s[7]; short4v* d[7]; };

__global__ __launch_bounds__(256) void cvt_all(CvtArgs a) {
  const int z = blockIdx.y;
  const int i = blockIdx.x * 256 + threadIdx.x;
  const float4 v = a.s[z][i];
  short4v o = { f2bf(v.x), f2bf(v.y), f2bf(v.z), f2bf(v.w) };
  a.d[z][i] = o;
}

// ------------------------------- GEMM modes ---------------------------------
enum { M_PROJ = 0, M_PROJV = 1, M_SCORES = 2, M_OUT = 3 };

template <int MODE>
__global__ __launch_bounds__(256) void gemm_nt(const short* __restrict__ Ap,
                                               const short* __restrict__ Bp,
                                               void* __restrict__ Cp) {
  constexpr int K   = (MODE == M_OUT) ? 2048 : 512;   // k-loop extent
  constexpr int LDA = (MODE == M_OUT) ? 4096 : 512;   // A row stride
  constexpr int LDB = (MODE == M_OUT) ? 4096 : 512;   // B row stride

  __shared__ short As[128 * 32];  // 8 KB
  __shared__ short Bs[128 * 32];  // 8 KB

  const int t = threadIdx.x;
  const int lane = t & 63;
  const int wv = t >> 6;          // wave 0..3
  const int wm = wv >> 1, wn = wv & 1;
  const int z = blockIdx.z;

  size_t Aoff, Boff;
  if constexpr (MODE == M_PROJ || MODE == M_PROJV) {
    Aoff = (size_t)(z >> 3) * ((size_t)cL * cD);   // per-b input
    Boff = (size_t)(z & 7) * ((size_t)cD * cD);    // per-h weight
  } else if constexpr (MODE == M_SCORES) {
    Aoff = (size_t)z * ((size_t)cL * cD);          // qh[b,h]
    Boff = (size_t)z * ((size_t)cL * cD);          // kh[b,h]
  } else {                                         // M_OUT split-K: z = b*2+khalf
    Aoff = (size_t)(z >> 1) * ((size_t)cL * 4096) + (size_t)(z & 1) * 2048;
    Boff = (size_t)(z & 1) * 2048;
  }

  const short* Ag0 = Ap + Aoff + (size_t)(blockIdx.y * 128) * LDA;
  const short* Bg0 = Bp + Boff + (size_t)(blockIdx.x * 128) * LDB;

  f32x4 acc[4][4];
#pragma unroll
  for (int i = 0; i < 4; ++i)
#pragma unroll
    for (int j = 0; j < 4; ++j) acc[i][j] = (f32x4){0.f, 0.f, 0.f, 0.f};

  for (int kt = 0; kt < K; kt += 32) {
    __syncthreads();  // LDS safe to overwrite
#pragma unroll
    for (int r = 0; r < 2; ++r) {
      const int cbase = r * 256 + wv * 64;    // wave-uniform chunk base
      const int c = cbase + lane;             // 0..511 16B chunks
      const int row = c >> 2, col = (c & 3) * 8;
      gload16(Ag0 + (size_t)row * LDA + kt + col, &As[cbase * 8]);
    }
#pragma unroll
    for (int r = 0; r < 2; ++r) {
      const int cbase = r * 256 + wv * 64;
      const int c = cbase + lane;
      const int row = c >> 2, col = (c & 3) * 8;
      gload16(Bg0 + (size_t)row * LDB + kt + col, &Bs[cbase * 8]);
    }
    __syncthreads();  // staging complete

    const int koff = (lane >> 4) * 8;           // A/B frag: k = quad*8 + j
    const int ar = wm * 64 + (lane & 15);
    const int br = wn * 64 + (lane & 15);
    bf16x8 af[4], bfv[4];
#pragma unroll
    for (int i = 0; i < 4; ++i) af[i] = *(const bf16x8*)&As[(ar + i * 16) * 32 + koff];
#pragma unroll
    for (int j = 0; j < 4; ++j) bfv[j] = *(const bf16x8*)&Bs[(br + j * 16) * 32 + koff];
#pragma unroll
    for (int i = 0; i < 4; ++i)
#pragma unroll
      for (int j = 0; j < 4; ++j)
        acc[i][j] = __builtin_amdgcn_mfma_f32_16x16x32_bf16(af[i], bfv[j], acc[i][j], 0, 0, 0);
  }

  // ---- epilogue: C/D layout col=lane&15, row=(lane>>4)*4+reg ----
  const int r0 = (lane >> 4) * 4;
  const int cc = lane & 15;
  const int rowbase = blockIdx.y * 128 + wm * 64 + r0;
  const int colbase = blockIdx.x * 128 + wn * 64 + cc;

  if constexpr (MODE == M_PROJ) {
    short* C = (short*)Cp + (size_t)z * ((size_t)cL * cD);
#pragma unroll
    for (int i = 0; i < 4; ++i)
#pragma unroll
      for (int j = 0; j < 4; ++j)
#pragma unroll
        for (int r = 0; r < 4; ++r)
          C[(size_t)(rowbase + i * 16 + r) * cD + (colbase + j * 16)] = f2bf(acc[i][j][r]);
  } else if constexpr (MODE == M_PROJV) {
    // store transposed: vhT[e][l]
    short* C = (short*)Cp + (size_t)z * ((size_t)cD * cL);
#pragma unroll
    for (int i = 0; i < 4; ++i)
#pragma unroll
      for (int j = 0; j < 4; ++j) {
        short4v o = { f2bf(acc[i][j][0]), f2bf(acc[i][j][1]),
                      f2bf(acc[i][j][2]), f2bf(acc[i][j][3]) };
        *(short4v*)&C[(size_t)(colbase + j * 16) * cL + (rowbase + i * 16)] = o;
      }
  } else if constexpr (MODE == M_SCORES) {
    float* C = (float*)Cp + (size_t)z * ((size_t)cL * cL);
#pragma unroll
    for (int i = 0; i < 4; ++i)
#pragma unroll
      for (int j = 0; j < 4; ++j)
#pragma unroll
        for (int r = 0; r < 4; ++r)
          C[(size_t)(rowbase + i * 16 + r) * cL + (colbase + j * 16)] =
              acc[i][j][r] * SCORE_SCALE;
  } else {  // M_OUT: fp32 partial (khalf) into ws
    float* C = (float*)Cp + (size_t)((z & 1) * 2 + (z >> 1)) * ((size_t)cL * cD);
#pragma unroll
    for (int i = 0; i < 4; ++i)
#pragma unroll
      for (int j = 0; j < 4; ++j)
#pragma unroll
        for (int r = 0; r < 4; ++r)
          C[(size_t)(rowbase + i * 16 + r) * cD + (colbase + j * 16)] = acc[i][j][r];
  }
}

// -------------------- per-row softmax stats (m, 1/l) ------------------------
__global__ __launch_bounds__(256) void row_stats(const float* __restrict__ attn,
                                                 float2* __restrict__ stats) {
  const int row = blockIdx.x * 4 + (threadIdx.x >> 6);
  const int lane = threadIdx.x & 63;
  const float4* p = (const float4*)(attn + (size_t)row * cL);
  float4 v[8];
#pragma unroll
  for (int r = 0; r < 8; ++r) v[r] = p[lane + 64 * r];
  float m = -1e30f;
#pragma unroll
  for (int r = 0; r < 8; ++r)
    m = fmaxf(m, fmaxf(fmaxf(v[r].x, v[r].y), fmaxf(v[r].z, v[r].w)));
#pragma unroll
  for (int off = 32; off; off >>= 1) m = fmaxf(m, __shfl_xor(m, off, 64));
  float s = 0.f;
#pragma unroll
  for (int r = 0; r < 8; ++r)
    s += __expf(v[r].x - m) + __expf(v[r].y - m) +
         __expf(v[r].z - m) + __expf(v[r].w - m);
#pragma unroll
  for (int off = 32; off; off >>= 1) s += __shfl_xor(s, off, 64);
  if (lane == 0) stats[row] = make_float2(m, 1.0f / s);
}

// ---------------- fused softmax-normalize (in place) + ctx ------------------
// grid (rowblk=16, z=16), 512 threads = 8 waves (2 M x 4 N), wave tile 64x128.
// Each block owns a full 128-row x 2048-k score strip -> in-place s->p is safe.
__global__ __launch_bounds__(512) void fused_ctx(const short* __restrict__ vhT,
                                                 const float2* __restrict__ stats,
                                                 float* __restrict__ attn,
                                                 short* __restrict__ comb) {
  __shared__ short Pb[128 * 32];  //  8 KB transformed attn (bf16), XOR-swizzled
  __shared__ short Bs[512 * 32];  // 32 KB vhT tile, XOR-swizzled

  const int t = threadIdx.x;
  const int lane = t & 63;
  const int wv = t >> 6;          // 0..7
  const int wm = wv >> 2, wn = wv & 3;
  const int rowblk = blockIdx.x;  // 0..15
  const int z = blockIdx.y;       // b*8+h

  // transform-thread coords: thread owns (row = t>>2, k-chunk (t&3)*8 + kt)
  const int trow = t >> 2;                    // 0..127
  const int tcb = t & 3;                      // which chunk-of-8 in the 32-tile
  const int tslot = tcb ^ (trow & 3);         // swizzled LDS slot
  const int grow = rowblk * 128 + trow;
  float* sp = attn + ((size_t)z * cL + grow) * cL + tcb * 8;
  const float2 st = stats[(size_t)z * cL + grow];
  const float m = st.x, invl = st.y;

  const short* Bg = vhT + (size_t)z * ((size_t)cD * cL);

  f32x4 acc[4][8];
#pragma unroll
  for (int i = 0; i < 4; ++i)
#pragma unroll
    for (int j = 0; j < 8; ++j) acc[i][j] = (f32x4){0.f, 0.f, 0.f, 0.f};

  const int sw = ((lane >> 4) ^ (lane & 3)) * 8;  // swizzled frag k-slot
  const int ar = wm * 64 + (lane & 15);
  const int br = wn * 128 + (lane & 15);

  float4 c0 = *(const float4*)(sp);
  float4 c1 = *(const float4*)(sp + 4);

  for (int kt = 0; kt < cL; kt += 32) {
    __syncthreads();  // LDS consumers of previous tile are done
    // ---- stage B (vhT) async; swizzle applied on the SOURCE column ----
#pragma unroll
    for (int r = 0; r < 4; ++r) {
      const int cbase = r * 512 + wv * 64;   // wave-uniform base
      const int c = cbase + lane;            // 0..2047 16B chunks
      const int row = c >> 2;
      const int swcol = ((c & 3) ^ (row & 3)) * 8;
      gload16(Bg + (size_t)row * cL + kt + swcol, &Bs[cbase * 8]);
    }
    // ---- transform s->p, write attn fp32 in place, stage bf16 into Pb ----
    {
      const float p0 = __expf(c0.x - m) * invl;
      const float p1 = __expf(c0.y - m) * invl;
      const float p2 = __expf(c0.z - m) * invl;
      const float p3 = __expf(c0.w - m) * invl;
      const float p4 = __expf(c1.x - m) * invl;
      const float p5 = __expf(c1.y - m) * invl;
      const float p6 = __expf(c1.z - m) * invl;
      const float p7 = __expf(c1.w - m) * invl;
      *(float4*)(sp + kt)     = make_float4(p0, p1, p2, p3);
      *(float4*)(sp + kt + 4) = make_float4(p4, p5, p6, p7);
      bf16x8 pb = { f2bf(p0), f2bf(p1), f2bf(p2), f2bf(p3),
                    f2bf(p4), f2bf(p5), f2bf(p6), f2bf(p7) };
      *(bf16x8*)&Pb[trow * 32 + tslot * 8] = pb;
      if (kt + 32 < cL) {  // prefetch next chunk (hidden under MFMA phase)
        c0 = *(const float4*)(sp + kt + 32);
        c1 = *(const float4*)(sp + kt + 36);
      }
    }
    __syncthreads();  // Pb ds_writes + Bs DMA drained

    bf16x8 af[4], bfv[8];
#pragma unroll
    for (int i = 0; i < 4; ++i) af[i] = *(const bf16x8*)&Pb[(ar + i * 16) * 32 + sw];
#pragma unroll
    for (int j = 0; j < 8; ++j) bfv[j] = *(const bf16x8*)&Bs[(br + j * 16) * 32 + sw];
#pragma unroll
    for (int i = 0; i < 4; ++i)
#pragma unroll
      for (int j = 0; j < 8; ++j)
        acc[i][j] = __builtin_amdgcn_mfma_f32_16x16x32_bf16(af[i], bfv[j], acc[i][j], 0, 0, 0);
  }

  // ---- epilogue -> comb permuted layout: j = (e>>6)*512 + h*64 + (e&63) ----
  const int r0 = (lane >> 4) * 4;
  const int cc = lane & 15;
  short* C = comb + (size_t)(z >> 3) * ((size_t)cL * (cH * cD));
  const int h = z & 7;
  const int rowbase = rowblk * 128 + wm * 64 + r0;
#pragma unroll
  for (int i = 0; i < 4; ++i)
#pragma unroll
    for (int j = 0; j < 8; ++j) {
      const int e = wn * 128 + j * 16 + cc;
      const int jc = ((e >> 6) << 9) + (h << 6) + (e & 63);
#pragma unroll
      for (int r = 0; r < 4; ++r)
        C[(size_t)(rowbase + i * 16 + r) * (cH * cD) + jc] = f2bf(acc[i][j][r]);
    }
}

// --------------------- sum the two split-K partials -------------------------
__global__ __launch_bounds__(256) void add_halves(const float4* __restrict__ p,
                                                  float4* __restrict__ out) {
  const int i = blockIdx.x * 256 + threadIdx.x;
  const float4 a = p[i];
  const float4 b = p[i + (cB * cL * cD) / 4];
  out[i] = make_float4(a.x + b.x, a.y + b.y, a.z + b.z, a.w + b.w);
}

// --------------------------------- launch -----------------------------------
extern "C" void kernel_launch(void* const* d_in, const int* in_sizes, int n_in,
                              void* d_out, int out_size, void* d_ws, size_t ws_size,
                              hipStream_t stream) {
  (void)in_sizes; (void)n_in; (void)out_size;

  const float* q  = (const float*)d_in[0];
  const float* k  = (const float*)d_in[1];
  const float* v  = (const float*)d_in[2];
  const float* Wq = (const float*)d_in[3];
  const float* Wk = (const float*)d_in[4];
  const float* Wv = (const float*)d_in[5];
  const float* Wo = (const float*)d_in[6];

  float* out  = (float*)d_out;
  float* attn = out + (size_t)cB * cL * cD;  // 2,097,152 floats in

  constexpr size_t Mi = 1ull << 20;
  char* ws = (char*)d_ws;
  short* qbf = (short*)(ws + 0 * Mi);
  short* kbf = (short*)(ws + 4 * Mi);
  short* vbf = (short*)(ws + 8 * Mi);
  short* wqb = (short*)(ws + 12 * Mi);
  short* wkb = (short*)(ws + 16 * Mi);
  short* wvb = (short*)(ws + 20 * Mi);
  short* wob = (short*)(ws + 24 * Mi);
  short* qh  = (short*)(ws + 28 * Mi);   // 32 MiB; dead after scores
  short* kh  = (short*)(ws + 60 * Mi);   // 32 MiB; dead after scores
  short* vhT = (short*)(ws + 92 * Mi);   // 32 MiB
  short* comb = qh;                      // alias: written after qh dead
  float2* stats = (float2*)(ws + 0 * Mi);// alias qbf (dead after projections)
  float*  pout  = (float*)(ws + 60 * Mi);// alias kh (dead after scores), 16 MiB

  if (ws_size < 124 * Mi) {
    fprintf(stderr, "kernel_launch: ws too small (%zu < %zu)\n", ws_size, 124 * Mi);
    return;
  }

  // 1) convert inputs/weights to bf16 (7 same-size tensors, one launch)
  CvtArgs ca;
  ca.s[0] = (const float4*)q;  ca.d[0] = (short4v*)qbf;
  ca.s[1] = (const float4*)k;  ca.d[1] = (short4v*)kbf;
  ca.s[2] = (const float4*)v;  ca.d[2] = (short4v*)vbf;
  ca.s[3] = (const float4*)Wq; ca.d[3] = (short4v*)wqb;
  ca.s[4] = (const float4*)Wk; ca.d[4] = (short4v*)wkb;
  ca.s[5] = (const float4*)Wv; ca.d[5] = (short4v*)wvb;
  ca.s[6] = (const float4*)Wo; ca.d[6] = (short4v*)wob;
  cvt_all<<<dim3(2048, 7), 256, 0, stream>>>(ca);

  // 2) per-head projections (z = b*8+h), M=2048 N=512 K=512
  gemm_nt<M_PROJ ><<<dim3(4, 16, 16), 256, 0, stream>>>(qbf, wqb, qh);
  gemm_nt<M_PROJ ><<<dim3(4, 16, 16), 256, 0, stream>>>(kbf, wkb, kh);
  gemm_nt<M_PROJV><<<dim3(4, 16, 16), 256, 0, stream>>>(vbf, wvb, vhT);

  // 3) scores -> d_out attn region (fp32, scaled), M=N=2048 K=512
  gemm_nt<M_SCORES><<<dim3(16, 16, 16), 256, 0, stream>>>(qh, kh, attn);

  // 4) per-row softmax stats (m, 1/l)
  row_stats<<<cB * cH * cL / 4, 256, 0, stream>>>(attn, stats);

  // 5) fused: normalize attn in place + ctx -> comb
  fused_ctx<<<dim3(16, cB * cH), 512, 0, stream>>>(vhT, stats, attn, comb);

  // 6) out = comb @ Wo^T, split-K x2 (z = b*2 + khalf) -> fp32 partials
  gemm_nt<M_OUT><<<dim3(4, 16, 4), 256, 0, stream>>>(comb, wob, (void*)pout);

  // 7) out = partial0 + partial1
  add_halves<<<2048, 256, 0, stream>>>((const float4*)pout, (float4*)out);
}